// Round 13
// baseline (111.408 us; speedup 1.0000x reference)
//
#include <hip/hip_runtime.h>
#include <hip/hip_bf16.h>

using bf16 = __hip_bfloat16;
typedef __attribute__((ext_vector_type(8))) short short8;
typedef __attribute__((ext_vector_type(4))) float f32x4;

static constexpr int C = 768, T = 1024, H = 12, D = 64;

__device__ __forceinline__ f32x4 mfma16(short8 a, short8 b, f32x4 c){
  return __builtin_amdgcn_mfma_f32_16x16x32_bf16(a, b, c, 0, 0, 0);
}

__device__ __forceinline__ void gload16(const void* g, void* l){
  void* gv = const_cast<void*>(g);
  __builtin_amdgcn_global_load_lds((__attribute__((address_space(1))) void*)gv,
                                   (__attribute__((address_space(3))) void*)l, 16, 0, 0);
}

__device__ __forceinline__ float b2f(short s){
  unsigned u = ((unsigned)(unsigned short)s) << 16;
  return __builtin_bit_cast(float, u);
}

// pack two f32 -> one u32 of 2 bf16 (lo = a, hi = b)
__device__ __forceinline__ int cvtpk(float a, float b){
  int r;
  asm("v_cvt_pk_bf16_f32 %0, %1, %2" : "=v"(r) : "v"(a), "v"(b));
  return r;
}

union PkU { int i[4]; short8 v; };

// ---- prep: [B][C][T] f32 -> [B][T][C] bf16 transposes (z<8) + 4 weight cvts ----
__global__ __launch_bounds__(256) void prep_kernel(const float* __restrict__ xin,
    const float* __restrict__ cin, const float* __restrict__ Wq,
    const float* __restrict__ Wk, const float* __restrict__ Wv,
    const float* __restrict__ Wo, bf16* __restrict__ xo, bf16* __restrict__ co,
    bf16* __restrict__ wq, bf16* __restrict__ wk, bf16* __restrict__ wv,
    bf16* __restrict__ wo){
  const int z = blockIdx.z;
  if (z < 8){
    __shared__ float tile[64][65];
    const int b = z & 3, which = z >> 2;
    const float* in = which ? cin : xin;
    bf16* out = which ? co : xo;
    const int t0 = blockIdx.x*64, c0 = blockIdx.y*64;
    const int u = threadIdx.x & 63, r0 = threadIdx.x >> 6;
    const float* ip = in + ((size_t)b*C + c0)*T + t0;
    #pragma unroll
    for (int i = r0; i < 64; i += 4) tile[i][u] = ip[(size_t)i*T + u];
    __syncthreads();
    bf16* op = out + ((size_t)b*T + t0)*C + c0;
    #pragma unroll
    for (int j = r0; j < 64; j += 4) op[(size_t)j*C + u] = (bf16)tile[u][j];
  } else {
    const int chunk = (z - 8)*192 + blockIdx.y*16 + blockIdx.x;   // 0..2303
    const int m = chunk / 576;
    const int off = (chunk % 576)*1024 + threadIdx.x*4;
    const float* in = m==0 ? Wq : m==1 ? Wk : m==2 ? Wv : Wo;
    bf16* out = m==0 ? wq : m==1 ? wk : m==2 ? wv : wo;
    float4 v = *(const float4*)(in + off);
    out[off+0] = (bf16)v.x; out[off+1] = (bf16)v.y;
    out[off+2] = (bf16)v.z; out[off+3] = (bf16)v.w;
  }
}

// ---- merged Q/K/V projection GEMM: 128x128 tile, BK=64, swizzled LDS ----
// Q is scaled by 0.125 * log2(e) so attention scores live in log2 domain.
// Modes 0/1: m0=(lb%8) so same-A-panel blocks land on the same XCD (48%8==0).
__global__ __launch_bounds__(256,3) void gemm_qkv(const bf16* __restrict__ xb,
    const bf16* __restrict__ cb, const bf16* __restrict__ wq, const bf16* __restrict__ wk,
    const bf16* __restrict__ wv, const float* __restrict__ bq, const float* __restrict__ bk,
    const float* __restrict__ bv, bf16* __restrict__ qout, bf16* __restrict__ kout,
    bf16* __restrict__ vout){
  const int tid = threadIdx.x, lane = tid & 63, w = tid >> 6;
  const int wr = w >> 1, wc = w & 1, g = lane >> 4, cl = lane & 15;
  const int bz = blockIdx.y, b = bz & 3, mode = bz >> 2;
  const int lb = blockIdx.x;
  int m0, n0;
  if (mode == 2){ m0 = (lb >> 3)*128; n0 = (lb & 7)*128; }
  else          { m0 = (lb & 7)*128;  n0 = (lb >> 3)*128; }
  const bf16* A  = (mode==0) ? xb + (size_t)b*T*C : (mode==1) ? cb + (size_t)b*T*C : wv;
  const bf16* Bp = (mode==2) ? cb + (size_t)b*T*C : (mode==0) ? wq : wk;
  const float* bias = (mode==0) ? bq : (mode==1) ? bk : bv;
  const float scale = (mode==0) ? 0.125f*1.44269504088896f : 1.0f;
  __shared__ bf16 lA[128*64], lB[128*64];
  f32x4 acc[4][4] = {};
  const bf16* Ars = A  + (size_t)m0*768;
  const bf16* Brs = Bp + (size_t)n0*768;
  for (int k0 = 0; k0 < 768; k0 += 64){
    __syncthreads();
    #pragma unroll
    for (int rr = 0; rr < 4; ++rr){
      const int u = rr*256 + tid;
      const int row = u >> 3, cc = u & 7;
      const int src = row*768 + k0 + ((cc ^ (row & 7))*8);
      gload16(Ars + src, &lA[(size_t)u*8]);
      gload16(Brs + src, &lB[(size_t)u*8]);
    }
    __syncthreads();
    #pragma unroll
    for (int kh = 0; kh < 2; ++kh){
      short8 af[4], bfr[4];
      #pragma unroll
      for (int mi = 0; mi < 4; ++mi){
        const int row = wr*64 + mi*16 + cl;
        af[mi] = *(const short8*)&lA[row*64 + (((g + kh*4) ^ (row & 7))*8)];
      }
      #pragma unroll
      for (int ni = 0; ni < 4; ++ni){
        const int row = wc*64 + ni*16 + cl;
        bfr[ni] = *(const short8*)&lB[row*64 + (((g + kh*4) ^ (row & 7))*8)];
      }
      __builtin_amdgcn_s_setprio(1);
      #pragma unroll
      for (int mi = 0; mi < 4; ++mi)
        #pragma unroll
        for (int ni = 0; ni < 4; ++ni)
          acc[mi][ni] = mfma16(af[mi], bfr[ni], acc[mi][ni]);
      __builtin_amdgcn_s_setprio(0);
    }
  }
  #pragma unroll
  for (int mi = 0; mi < 4; ++mi){
    const int mB = m0 + wr*64 + mi*16 + g*4;
    #pragma unroll
    for (int ni = 0; ni < 4; ++ni){
      const int n = n0 + wc*64 + ni*16 + cl;
      #pragma unroll
      for (int r = 0; r < 4; ++r){
        const int m = mB + r;
        float v = acc[mi][ni][r];
        if (mode <= 1){
          v = (v + bias[n]) * scale;
          bf16* outp = mode ? kout : qout;
          outp[(size_t)b*(H*T*D) + (size_t)(n >> 6)*(T*D) + (size_t)m*D + (n & 63)] = (bf16)v;
        } else {
          v += bias[m];
          vout[(size_t)b*(C*T) + (size_t)m*T + n] = (bf16)v;
        }
      }
    }
  }
}

// ---- output projection GEMM (f32 out); same-B-panel blocks co-located on XCD ----
__global__ __launch_bounds__(256,3) void gemm_o(const bf16* __restrict__ wo,
                                                const bf16* __restrict__ attn,
                                                const float* __restrict__ bias,
                                                float* __restrict__ outp){
  const int tid = threadIdx.x, lane = tid & 63, w = tid >> 6;
  const int wr = w >> 1, wc = w & 1, g = lane >> 4, cl = lane & 15;
  const int b = blockIdx.z;
  const int q = blockIdx.y*6 + blockIdx.x;      // 0..47
  const int m0 = (q >> 3)*128, n0 = (q & 7)*128;
  __shared__ bf16 lA[128*64], lB[128*64];
  f32x4 acc[4][4] = {};
  const bf16* Ars = wo + (size_t)m0*768;
  const bf16* Brs = attn + (size_t)b*T*C + (size_t)n0*768;
  for (int k0 = 0; k0 < 768; k0 += 64){
    __syncthreads();
    #pragma unroll
    for (int rr = 0; rr < 4; ++rr){
      const int u = rr*256 + tid;
      const int row = u >> 3, cc = u & 7;
      const int src = row*768 + k0 + ((cc ^ (row & 7))*8);
      gload16(Ars + src, &lA[(size_t)u*8]);
      gload16(Brs + src, &lB[(size_t)u*8]);
    }
    __syncthreads();
    #pragma unroll
    for (int kh = 0; kh < 2; ++kh){
      short8 af[4], bfr[4];
      #pragma unroll
      for (int mi = 0; mi < 4; ++mi){
        const int row = wr*64 + mi*16 + cl;
        af[mi] = *(const short8*)&lA[row*64 + (((g + kh*4) ^ (row & 7))*8)];
      }
      #pragma unroll
      for (int ni = 0; ni < 4; ++ni){
        const int row = wc*64 + ni*16 + cl;
        bfr[ni] = *(const short8*)&lB[row*64 + (((g + kh*4) ^ (row & 7))*8)];
      }
      __builtin_amdgcn_s_setprio(1);
      #pragma unroll
      for (int mi = 0; mi < 4; ++mi)
        #pragma unroll
        for (int ni = 0; ni < 4; ++ni)
          acc[mi][ni] = mfma16(af[mi], bfr[ni], acc[mi][ni]);
      __builtin_amdgcn_s_setprio(0);
    }
  }
  #pragma unroll
  for (int mi = 0; mi < 4; ++mi){
    const int mB = m0 + wr*64 + mi*16 + g*4;
    #pragma unroll
    for (int ni = 0; ni < 4; ++ni){
      const int n = n0 + wc*64 + ni*16 + cl;
      #pragma unroll
      for (int r = 0; r < 4; ++r){
        const int m = mB + r;
        outp[(size_t)b*(C*T) + (size_t)m*T + n] = acc[mi][ni][r] + bias[m];
      }
    }
  }
}

// ---- fused attention: transposed-P, K direct-from-global into registers
//      (8KB K-tile is L1-resident; sigma folded into per-lane address, loads
//      for tile t+1 issue right after QK(t) frees the regs), V LDS dbuf with
//      counted-vmcnt two-barrier pipeline. LDS 24.6KB. ----
__global__ __launch_bounds__(256,3) void attn_kernel(const bf16* __restrict__ qws,
                                                     const bf16* __restrict__ kws,
                                                     const bf16* __restrict__ vws,
                                                     bf16* __restrict__ aws,
                                                     const float* __restrict__ relk,
                                                     const float* __restrict__ relv){
  const int tid = threadIdx.x, lane = tid & 63, w = tid >> 6;
  const int g = lane >> 4, cl = lane & 15;
  const int i0 = blockIdx.y*64, bh = blockIdx.x;   // bh fast -> same-bh blocks on one XCD
  const int b = bh / H, h = bh % H;
  const int ql = w*16 + cl;            // this lane's q row (block-local)
  const int qt = i0 + ql;              // global q row

  __shared__ __align__(16) char smem[24576];
  bf16*  vb0   = (bf16*)smem;                  // V buf 0 (8KB)
  bf16*  vb1   = (bf16*)(smem + 8192);         // V buf 1 (Q in prologue)
  float* bandS = (float*)(smem + 16384);       // [64][21] raw band scores (log2)
  bf16*  relkD = (bf16*)(smem + 21760);        // [64][22] per-row rel-k dots
  bf16*  lEmb32 = (bf16*)(smem + 16384);       // [32][64] prologue alias (bandS)
  bf16*  lQ     = vb1;                         // prologue alias
  bf16*  lEV    = vb0;                         // epilogue alias

  const bf16* qg = qws + ((size_t)bh*T + i0)*D;
  const bf16* kg = kws + (size_t)bh*T*D;
  const bf16* vg = vws + ((size_t)b*C + h*D)*T;

  // V/Q staging offsets (per lane, hoisted)
  int vOff[2], qOff[2], dst[2];
  #pragma unroll
  for (int r = 0; r < 2; ++r){
    const int u = r*256 + tid, L = u >> 3, cc = u & 7;
    const int sc8 = (cc ^ (L & 7))*8;
    vOff[r] = L*T + sc8;
    qOff[r] = L*64 + sc8;
    dst[r]  = u*8;
  }
  // K direct-load offsets: sigma row-permutation folded into per-lane address
  int koff[4];
  #pragma unroll
  for (int ni = 0; ni < 4; ++ni){
    const int row = ni*16 + cl;
    const int sigr = (((row>>4)&1)<<5) | (((row>>2)&3)<<3) | (((row>>5)&1)<<2) | (row&3);
    koff[ni] = sigr*64 + g*8;
  }

  #pragma unroll
  for (int r = 0; r < 2; ++r){
    gload16(qg + qOff[r], &lQ[dst[r]]);
    gload16(vg + vOff[r], &vb0[dst[r]]);
  }
  // stage rel-k embeddings as padded 32x64 bf16 tile (chunk-swizzled)
  for (int idx = tid; idx < 2048; idx += 256){
    const int row = idx >> 6, col = idx & 63;
    const float v = (row < 21) ? relk[idx] : 0.0f;
    lEmb32[row*64 + (((col >> 3) ^ (row & 7))*8) + (col & 7)] = (bf16)v;
  }
  // K(0) fragments direct into registers
  short8 kr[4][2];
  #pragma unroll
  for (int ni = 0; ni < 4; ++ni){
    kr[ni][0] = *(const short8*)(kg + koff[ni]);
    kr[ni][1] = *(const short8*)(kg + koff[ni] + 32);
  }
  __syncthreads();   // Q/V0/emb staged, K0 regs loaded (syncthreads drains vmcnt)

  const short8 aq0 = *(const short8*)&lQ[ql*64 + ((g ^ (ql & 7))*8)];
  const short8 aq1 = *(const short8*)&lQ[ql*64 + (((g + 4) ^ (ql & 7))*8)];

  // relk_dot via swapped MFMA: R^T[r][q], lane holds r = 16*ni2 + 4g + rr
  #pragma unroll
  for (int ni2 = 0; ni2 < 2; ++ni2){
    const int row = ni2*16 + cl;
    short8 e0 = *(const short8*)&lEmb32[row*64 + ((g ^ (row & 7))*8)];
    short8 e1 = *(const short8*)&lEmb32[row*64 + (((g + 4) ^ (row & 7))*8)];
    f32x4 rk = {};
    rk = mfma16(e0, aq0, rk);
    rk = mfma16(e1, aq1, rk);
    #pragma unroll
    for (int rr = 0; rr < 4; ++rr){
      const int ridx = ni2*16 + 4*g + rr;
      if (ridx < 21) relkD[ql*22 + ridx] = (bf16)rk[rr];
    }
  }
  __syncthreads();   // relkD visible; lQ (vb1) & lEmb32 (bandS area) now dead

  float mreg = -1e30f, lreg = 0.f;
  f32x4 o[4] = {};
  const int koffA[4] = {8*g, 32 + 8*g, 4 + 8*g, 36 + 8*g};

  for (int jt = 0; jt < 16; ++jt){
    const int j0 = jt*64, cur = jt & 1;
    // issue next V tile's staging; current V (issued last iter) + current K regs
    // (issued last iter) awaited with a COUNTED vmcnt (in-order retirement).
    if (jt < 15){
      const bf16* vgn = vg + j0 + 64;
      bf16* vdst = cur ? vb0 : vb1;
      gload16(vgn + vOff[0], &vdst[dst[0]]);
      gload16(vgn + vOff[1], &vdst[dst[1]]);
      asm volatile("s_waitcnt vmcnt(2)" ::: "memory");
    } else {
      asm volatile("s_waitcnt vmcnt(0)" ::: "memory");
    }
    asm volatile("s_barrier" ::: "memory");   // V(jt) staged block-wide

    // S^T tiles from K registers: lane holds 16 scores for its own q row
    f32x4 s[4];
    __builtin_amdgcn_s_setprio(1);
    #pragma unroll
    for (int ni = 0; ni < 4; ++ni){
      f32x4 a = {};
      a = mfma16(kr[ni][0], aq0, a);
      a = mfma16(kr[ni][1], aq1, a);
      s[ni] = a;
    }
    __builtin_amdgcn_s_setprio(0);

    // K regs free: issue K(jt+1) direct loads (per-wave, no barrier coupling)
    if (jt < 15){
      const bf16* kgn = kg + (size_t)(j0 + 64)*64;
      #pragma unroll
      for (int ni = 0; ni < 4; ++ni){
        kr[ni][0] = *(const short8*)(kgn + koff[ni]);
        kr[ni][1] = *(const short8*)(kgn + koff[ni] + 32);
      }
    }

    const int dj = j0 - i0;
    if (dj == 0 || dj == 64 || dj == -64){
      #pragma unroll
      for (int ni = 0; ni < 4; ++ni){
        const int ibase = j0 + koffA[ni] - qt;
        #pragma unroll
        for (int r = 0; r < 4; ++r){
          const int dd = ibase + r;
          float v = s[ni][r] - __log2f(fabsf((float)dd) + 1.0f);
          if ((unsigned)(dd + 10) <= 20u){
            v += b2f(*(const short*)&relkD[ql*22 + dd + 10]);
            bandS[ql*21 + dd + 10] = v;
          }
          s[ni][r] = v;
        }
      }
    } else {
      #pragma unroll
      for (int ni = 0; ni < 4; ++ni){
        const float fb = (float)(j0 + koffA[ni] - qt);
        #pragma unroll
        for (int r = 0; r < 4; ++r)
          s[ni][r] -= __log2f(fabsf(fb + (float)r) + 1.0f);
      }
    }

    // lane-local online softmax (log2 domain), defer-max threshold 8
    float m0 = fmaxf(fmaxf(s[0][0], s[0][1]), fmaxf(s[0][2], s[0][3]));
    float m1 = fmaxf(fmaxf(s[1][0], s[1][1]), fmaxf(s[1][2], s[1][3]));
    float m2 = fmaxf(fmaxf(s[2][0], s[2][1]), fmaxf(s[2][2], s[2][3]));
    float m3 = fmaxf(fmaxf(s[3][0], s[3][1]), fmaxf(s[3][2], s[3][3]));
    float mx = fmaxf(fmaxf(m0, m1), fmaxf(m2, m3));
    mx = fmaxf(mx, __shfl_xor(mx, 16));
    mx = fmaxf(mx, __shfl_xor(mx, 32));
    if (!__all(mx <= mreg + 8.0f)){
      const float mn = fmaxf(mreg, mx);
      const float sc = __builtin_amdgcn_exp2f(mreg - mn);
      lreg *= sc;
      #pragma unroll
      for (int di = 0; di < 4; ++di)
        #pragma unroll
        for (int r = 0; r < 4; ++r) o[di][r] *= sc;
      mreg = mn;
    }
    float rs = 0.f;
    #pragma unroll
    for (int ni = 0; ni < 4; ++ni)
      #pragma unroll
      for (int r = 0; r < 4; ++r){
        float p = __builtin_amdgcn_exp2f(s[ni][r] - mreg);
        s[ni][r] = p; rs += p;
      }
    rs += __shfl_xor(rs, 16);
    rs += __shfl_xor(rs, 32);
    lreg += rs;

    // pack P in-register: frag0 = {ni0, ni2}, frag1 = {ni1, ni3}
    PkU bf0, bf1;
    bf0.i[0] = cvtpk(s[0][0], s[0][1]); bf0.i[1] = cvtpk(s[0][2], s[0][3]);
    bf0.i[2] = cvtpk(s[2][0], s[2][1]); bf0.i[3] = cvtpk(s[2][2], s[2][3]);
    bf1.i[0] = cvtpk(s[1][0], s[1][1]); bf1.i[1] = cvtpk(s[1][2], s[1][3]);
    bf1.i[2] = cvtpk(s[3][0], s[3][1]); bf1.i[3] = cvtpk(s[3][2], s[3][3]);

    const bf16* Vc = cur ? vb1 : vb0;
    __builtin_amdgcn_s_setprio(1);
    #pragma unroll
    for (int di = 0; di < 4; ++di){
      const int vrow = di*16 + cl;
      short8 a0 = *(const short8*)&Vc[vrow*64 + ((g ^ (vrow & 7))*8)];
      o[di] = mfma16(a0, bf0.v, o[di]);
      short8 a1 = *(const short8*)&Vc[vrow*64 + (((g + 4) ^ (vrow & 7))*8)];
      o[di] = mfma16(a1, bf1.v, o[di]);
    }
    __builtin_amdgcn_s_setprio(0);
    asm volatile("s_barrier" ::: "memory");   // all reads of V(jt) done
  }

  // epilogue: rel-v band contribution via MFMA (A staged over dead vb0)
  for (int idx = tid; idx < 2048; idx += 256){
    const int d = idx >> 5, c = idx & 31;
    const float v = (c < 21) ? relv[c*64 + d] : 0.0f;
    lEV[d*32 + (((c >> 3) ^ ((d >> 2) & 3))*8) + (c & 7)] = (bf16)v;
  }
  __syncthreads();

  const float invl = 1.0f / lreg;
  float pb[8];
  #pragma unroll
  for (int e = 0; e < 8; ++e){
    const int ddi = 8*g + e;
    float pv = 0.f;
    if (ddi < 21){
      const int j = qt + ddi - 10;
      if (j >= 0 && j < T)
        pv = __builtin_amdgcn_exp2f(bandS[ql*21 + ddi] - mreg) * invl;
    }
    pb[e] = pv;
  }
  PkU bfE;
  bfE.i[0] = cvtpk(pb[0], pb[1]); bfE.i[1] = cvtpk(pb[2], pb[3]);
  bfE.i[2] = cvtpk(pb[4], pb[5]); bfE.i[3] = cvtpk(pb[6], pb[7]);

  bf16* outp = aws + (size_t)(b*T + qt)*C + h*64;
  #pragma unroll
  for (int di = 0; di < 4; ++di){
    const int arow = di*16 + cl;
    short8 aE = *(const short8*)&lEV[arow*32 + ((g ^ ((arow >> 2) & 3))*8)];
    f32x4 z = {};
    f32x4 ba = mfma16(aE, bfE.v, z);
    const int p0 = cvtpk(o[di][0]*invl + ba[0], o[di][1]*invl + ba[1]);
    const int p1 = cvtpk(o[di][2]*invl + ba[2], o[di][3]*invl + ba[3]);
    *(int2*)(outp + di*16 + 4*g) = make_int2(p0, p1);
  }
}

extern "C" void kernel_launch(void* const* d_in, const int* in_sizes, int n_in,
                              void* d_out, int out_size, void* d_ws, size_t ws_size,
                              hipStream_t stream){
  const float* x    = (const float*)d_in[0];
  const float* cin  = (const float*)d_in[1];
  const float* Wq   = (const float*)d_in[2];
  const float* bq   = (const float*)d_in[3];
  const float* Wk   = (const float*)d_in[4];
  const float* bk   = (const float*)d_in[5];
  const float* Wv   = (const float*)d_in[6];
  const float* bv   = (const float*)d_in[7];
  const float* Wo   = (const float*)d_in[8];
  const float* bo   = (const float*)d_in[9];
  const float* relk = (const float*)d_in[10];
  const float* relv = (const float*)d_in[11];

  char* ws = (char*)d_ws;
  constexpr size_t SZ_W = (size_t)768*768*2;     // bf16 weight matrix
  constexpr size_t SZ_T = (size_t)4*1024*768*2;  // bf16 [B,T,C]-sized tensor
  bf16* wq  = (bf16*)(ws + 0*SZ_W);
  bf16* wk  = (bf16*)(ws + 1*SZ_W);
  bf16* wv  = (bf16*)(ws + 2*SZ_W);
  bf16* wo  = (bf16*)(ws + 3*SZ_W);
  bf16* xb  = (bf16*)(ws + 4*SZ_W);
  bf16* cb  = (bf16*)(ws + 4*SZ_W + 1*SZ_T);
  bf16* qws = (bf16*)(ws + 4*SZ_W + 2*SZ_T);
  bf16* kws = (bf16*)(ws + 4*SZ_W + 3*SZ_T);
  bf16* vws = (bf16*)(ws + 4*SZ_W + 4*SZ_T);
  bf16* attn = xb;   // alias: xb is dead after the Q projection

  prep_kernel<<<dim3(16,12,20), 256, 0, stream>>>(x, cin, Wq, Wk, Wv, Wo,
                                                  xb, cb, wq, wk, wv, wo);
  gemm_qkv<<<dim3(48,12), 256, 0, stream>>>(xb, cb, wq, wk, wv, bq, bk, bv, qws, kws, vws);
  attn_kernel<<<dim3(48,16), 256, 0, stream>>>(qws, kws, vws, attn, relk, relv);
  gemm_o<<<dim3(6,8,4), 256, 0, stream>>>(wo, attn, bo, (float*)d_out);
}

// Round 14
// 92.431 us; speedup vs baseline: 1.2053x; 1.2053x over previous
//
#include <hip/hip_runtime.h>
#include <hip/hip_bf16.h>

using bf16 = __hip_bfloat16;
typedef __attribute__((ext_vector_type(8))) short short8;
typedef __attribute__((ext_vector_type(4))) float f32x4;

static constexpr int C = 768, T = 1024, H = 12, D = 64;

__device__ __forceinline__ f32x4 mfma16(short8 a, short8 b, f32x4 c){
  return __builtin_amdgcn_mfma_f32_16x16x32_bf16(a, b, c, 0, 0, 0);
}

__device__ __forceinline__ void gload16(const void* g, void* l){
  void* gv = const_cast<void*>(g);
  __builtin_amdgcn_global_load_lds((__attribute__((address_space(1))) void*)gv,
                                   (__attribute__((address_space(3))) void*)l, 16, 0, 0);
}

__device__ __forceinline__ float b2f(short s){
  unsigned u = ((unsigned)(unsigned short)s) << 16;
  return __builtin_bit_cast(float, u);
}

// pack two f32 -> one u32 of 2 bf16 (lo = a, hi = b)
__device__ __forceinline__ int cvtpk(float a, float b){
  int r;
  asm("v_cvt_pk_bf16_f32 %0, %1, %2" : "=v"(r) : "v"(a), "v"(b));
  return r;
}

union PkU { int i[4]; short8 v; };

// ---- prep: [B][C][T] f32 -> [B][T][C] bf16 transposes (z<8) + 4 weight cvts ----
__global__ __launch_bounds__(256) void prep_kernel(const float* __restrict__ xin,
    const float* __restrict__ cin, const float* __restrict__ Wq,
    const float* __restrict__ Wk, const float* __restrict__ Wv,
    const float* __restrict__ Wo, bf16* __restrict__ xo, bf16* __restrict__ co,
    bf16* __restrict__ wq, bf16* __restrict__ wk, bf16* __restrict__ wv,
    bf16* __restrict__ wo){
  const int z = blockIdx.z;
  if (z < 8){
    __shared__ float tile[64][65];
    const int b = z & 3, which = z >> 2;
    const float* in = which ? cin : xin;
    bf16* out = which ? co : xo;
    const int t0 = blockIdx.x*64, c0 = blockIdx.y*64;
    const int u = threadIdx.x & 63, r0 = threadIdx.x >> 6;
    const float* ip = in + ((size_t)b*C + c0)*T + t0;
    #pragma unroll
    for (int i = r0; i < 64; i += 4) tile[i][u] = ip[(size_t)i*T + u];
    __syncthreads();
    bf16* op = out + ((size_t)b*T + t0)*C + c0;
    #pragma unroll
    for (int j = r0; j < 64; j += 4) op[(size_t)j*C + u] = (bf16)tile[u][j];
  } else {
    const int chunk = (z - 8)*192 + blockIdx.y*16 + blockIdx.x;   // 0..2303
    const int m = chunk / 576;
    const int off = (chunk % 576)*1024 + threadIdx.x*4;
    const float* in = m==0 ? Wq : m==1 ? Wk : m==2 ? Wv : Wo;
    bf16* out = m==0 ? wq : m==1 ? wk : m==2 ? wv : wo;
    float4 v = *(const float4*)(in + off);
    out[off+0] = (bf16)v.x; out[off+1] = (bf16)v.y;
    out[off+2] = (bf16)v.z; out[off+3] = (bf16)v.w;
  }
}

// ---- merged Q/K/V projection GEMM: 128x128 tile, BK=64, swizzled LDS ----
// Q is scaled by 0.125 * log2(e) so attention scores live in log2 domain.
// Modes 0/1: m0=(lb%8) so same-A-panel blocks land on the same XCD (48%8==0).
__global__ __launch_bounds__(256,3) void gemm_qkv(const bf16* __restrict__ xb,
    const bf16* __restrict__ cb, const bf16* __restrict__ wq, const bf16* __restrict__ wk,
    const bf16* __restrict__ wv, const float* __restrict__ bq, const float* __restrict__ bk,
    const float* __restrict__ bv, bf16* __restrict__ qout, bf16* __restrict__ kout,
    bf16* __restrict__ vout){
  const int tid = threadIdx.x, lane = tid & 63, w = tid >> 6;
  const int wr = w >> 1, wc = w & 1, g = lane >> 4, cl = lane & 15;
  const int bz = blockIdx.y, b = bz & 3, mode = bz >> 2;
  const int lb = blockIdx.x;
  int m0, n0;
  if (mode == 2){ m0 = (lb >> 3)*128; n0 = (lb & 7)*128; }
  else          { m0 = (lb & 7)*128;  n0 = (lb >> 3)*128; }
  const bf16* A  = (mode==0) ? xb + (size_t)b*T*C : (mode==1) ? cb + (size_t)b*T*C : wv;
  const bf16* Bp = (mode==2) ? cb + (size_t)b*T*C : (mode==0) ? wq : wk;
  const float* bias = (mode==0) ? bq : (mode==1) ? bk : bv;
  const float scale = (mode==0) ? 0.125f*1.44269504088896f : 1.0f;
  __shared__ bf16 lA[128*64], lB[128*64];
  f32x4 acc[4][4] = {};
  const bf16* Ars = A  + (size_t)m0*768;
  const bf16* Brs = Bp + (size_t)n0*768;
  for (int k0 = 0; k0 < 768; k0 += 64){
    __syncthreads();
    #pragma unroll
    for (int rr = 0; rr < 4; ++rr){
      const int u = rr*256 + tid;
      const int row = u >> 3, cc = u & 7;
      const int src = row*768 + k0 + ((cc ^ (row & 7))*8);
      gload16(Ars + src, &lA[(size_t)u*8]);
      gload16(Brs + src, &lB[(size_t)u*8]);
    }
    __syncthreads();
    #pragma unroll
    for (int kh = 0; kh < 2; ++kh){
      short8 af[4], bfr[4];
      #pragma unroll
      for (int mi = 0; mi < 4; ++mi){
        const int row = wr*64 + mi*16 + cl;
        af[mi] = *(const short8*)&lA[row*64 + (((g + kh*4) ^ (row & 7))*8)];
      }
      #pragma unroll
      for (int ni = 0; ni < 4; ++ni){
        const int row = wc*64 + ni*16 + cl;
        bfr[ni] = *(const short8*)&lB[row*64 + (((g + kh*4) ^ (row & 7))*8)];
      }
      __builtin_amdgcn_s_setprio(1);
      #pragma unroll
      for (int mi = 0; mi < 4; ++mi)
        #pragma unroll
        for (int ni = 0; ni < 4; ++ni)
          acc[mi][ni] = mfma16(af[mi], bfr[ni], acc[mi][ni]);
      __builtin_amdgcn_s_setprio(0);
    }
  }
  #pragma unroll
  for (int mi = 0; mi < 4; ++mi){
    const int mB = m0 + wr*64 + mi*16 + g*4;
    #pragma unroll
    for (int ni = 0; ni < 4; ++ni){
      const int n = n0 + wc*64 + ni*16 + cl;
      #pragma unroll
      for (int r = 0; r < 4; ++r){
        const int m = mB + r;
        float v = acc[mi][ni][r];
        if (mode <= 1){
          v = (v + bias[n]) * scale;
          bf16* outp = mode ? kout : qout;
          outp[(size_t)b*(H*T*D) + (size_t)(n >> 6)*(T*D) + (size_t)m*D + (n & 63)] = (bf16)v;
        } else {
          v += bias[m];
          vout[(size_t)b*(C*T) + (size_t)m*T + n] = (bf16)v;
        }
      }
    }
  }
}

// ---- output projection GEMM (f32 out); same-B-panel blocks co-located on XCD ----
__global__ __launch_bounds__(256,3) void gemm_o(const bf16* __restrict__ wo,
                                                const bf16* __restrict__ attn,
                                                const float* __restrict__ bias,
                                                float* __restrict__ outp){
  const int tid = threadIdx.x, lane = tid & 63, w = tid >> 6;
  const int wr = w >> 1, wc = w & 1, g = lane >> 4, cl = lane & 15;
  const int b = blockIdx.z;
  const int q = blockIdx.y*6 + blockIdx.x;      // 0..47
  const int m0 = (q >> 3)*128, n0 = (q & 7)*128;
  __shared__ bf16 lA[128*64], lB[128*64];
  f32x4 acc[4][4] = {};
  const bf16* Ars = wo + (size_t)m0*768;
  const bf16* Brs = attn + (size_t)b*T*C + (size_t)n0*768;
  for (int k0 = 0; k0 < 768; k0 += 64){
    __syncthreads();
    #pragma unroll
    for (int rr = 0; rr < 4; ++rr){
      const int u = rr*256 + tid;
      const int row = u >> 3, cc = u & 7;
      const int src = row*768 + k0 + ((cc ^ (row & 7))*8);
      gload16(Ars + src, &lA[(size_t)u*8]);
      gload16(Brs + src, &lB[(size_t)u*8]);
    }
    __syncthreads();
    #pragma unroll
    for (int kh = 0; kh < 2; ++kh){
      short8 af[4], bfr[4];
      #pragma unroll
      for (int mi = 0; mi < 4; ++mi){
        const int row = wr*64 + mi*16 + cl;
        af[mi] = *(const short8*)&lA[row*64 + (((g + kh*4) ^ (row & 7))*8)];
      }
      #pragma unroll
      for (int ni = 0; ni < 4; ++ni){
        const int row = wc*64 + ni*16 + cl;
        bfr[ni] = *(const short8*)&lB[row*64 + (((g + kh*4) ^ (row & 7))*8)];
      }
      __builtin_amdgcn_s_setprio(1);
      #pragma unroll
      for (int mi = 0; mi < 4; ++mi)
        #pragma unroll
        for (int ni = 0; ni < 4; ++ni)
          acc[mi][ni] = mfma16(af[mi], bfr[ni], acc[mi][ni]);
      __builtin_amdgcn_s_setprio(0);
    }
  }
  #pragma unroll
  for (int mi = 0; mi < 4; ++mi){
    const int mB = m0 + wr*64 + mi*16 + g*4;
    #pragma unroll
    for (int ni = 0; ni < 4; ++ni){
      const int n = n0 + wc*64 + ni*16 + cl;
      #pragma unroll
      for (int r = 0; r < 4; ++r){
        const int m = mB + r;
        outp[(size_t)b*(C*T) + (size_t)m*T + n] = acc[mi][ni][r] + bias[m];
      }
    }
  }
}

// ---- fused attention: transposed-P, K+V LDS double-buffer, counted-vmcnt
//      two-barrier pipeline. Grid (bh, i0) so all i0-blocks of one bh share
//      an XCD -> K/V L2-resident. Off-band bias linearized (|dd|>=65). ----
__global__ __launch_bounds__(256,4) void attn_kernel(const bf16* __restrict__ qws,
                                                     const bf16* __restrict__ kws,
                                                     const bf16* __restrict__ vws,
                                                     bf16* __restrict__ aws,
                                                     const float* __restrict__ relk,
                                                     const float* __restrict__ relv){
  const int tid = threadIdx.x, lane = tid & 63, w = tid >> 6;
  const int g = lane >> 4, cl = lane & 15;
  const int i0 = blockIdx.y*64, bh = blockIdx.x;   // bh fast -> same-bh blocks on one XCD
  const int b = bh / H, h = bh % H;
  const int ql = w*16 + cl;            // this lane's q row (block-local)
  const int qt = i0 + ql;              // global q row

  __shared__ __align__(16) char smem[40960];
  bf16*  lKV   = (bf16*)smem;                  // 4 bufs x 4096: K0,K1,V0,V1(=Q)
  float* bandS = (float*)(smem + 32768);       // [64][21] raw band scores (log2)
  bf16*  relkD = (bf16*)(smem + 38144);        // [64][22] per-row rel-k dots
  bf16*  lEmb32 = lKV + 4096;                  // [32][64] prologue alias (buf1)
  bf16*  lEV    = lKV;                         // [64][32] epilogue alias (buf0)
  bf16*  lQ     = lKV + 3*4096;                // buf3

  const bf16* qg = qws + ((size_t)bh*T + i0)*D;
  const bf16* kg = kws + (size_t)bh*T*D;
  const bf16* vg = vws + ((size_t)b*C + h*D)*T;

  // staging offsets (per lane, hoisted). K rows permuted by sigma so that a
  // lane's 16 S^T values form two 8-consecutive-k runs for the PV B-fragment.
  int kOff[2], vOff[2], qOff[2], dst[2];
  #pragma unroll
  for (int r = 0; r < 2; ++r){
    const int u = r*256 + tid, L = u >> 3, cc = u & 7;
    const int sc8 = (cc ^ (L & 7))*8;
    const int sig = (((L>>4)&1)<<5) | (((L>>2)&3)<<3) | (((L>>5)&1)<<2) | (L&3);
    kOff[r] = sig*64 + sc8;
    vOff[r] = L*T + sc8;
    qOff[r] = L*64 + sc8;
    dst[r]  = u*8;
  }

  #pragma unroll
  for (int r = 0; r < 2; ++r){
    gload16(qg + qOff[r], &lQ[dst[r]]);
    gload16(kg + kOff[r], &lKV[dst[r]]);
    gload16(vg + vOff[r], &lKV[2*4096 + dst[r]]);
  }
  // stage rel-k embeddings as padded 32x64 bf16 tile (chunk-swizzled)
  for (int idx = tid; idx < 2048; idx += 256){
    const int row = idx >> 6, col = idx & 63;
    const float v = (row < 21) ? relk[idx] : 0.0f;
    lEmb32[row*64 + (((col >> 3) ^ (row & 7))*8) + (col & 7)] = (bf16)v;
  }
  __syncthreads();

  const short8 aq0 = *(const short8*)&lQ[ql*64 + ((g ^ (ql & 7))*8)];
  const short8 aq1 = *(const short8*)&lQ[ql*64 + (((g + 4) ^ (ql & 7))*8)];

  // relk_dot via swapped MFMA: R^T[r][q], lane holds r = 16*ni2 + 4g + rr
  #pragma unroll
  for (int ni2 = 0; ni2 < 2; ++ni2){
    const int row = ni2*16 + cl;
    short8 e0 = *(const short8*)&lEmb32[row*64 + ((g ^ (row & 7))*8)];
    short8 e1 = *(const short8*)&lEmb32[row*64 + (((g + 4) ^ (row & 7))*8)];
    f32x4 rk = {};
    rk = mfma16(e0, aq0, rk);
    rk = mfma16(e1, aq1, rk);
    #pragma unroll
    for (int rr = 0; rr < 4; ++rr){
      const int ridx = ni2*16 + 4*g + rr;
      if (ridx < 21) relkD[ql*22 + ridx] = (bf16)rk[rr];
    }
  }
  __syncthreads();   // relkD visible; lQ (buf3) & lEmb32 (buf1) free for V1/K1

  float mreg = -1e30f, lreg = 0.f;
  f32x4 o[4] = {};
  const int koffA[4] = {8*g, 32 + 8*g, 4 + 8*g, 36 + 8*g};

  for (int jt = 0; jt < 16; ++jt){
    const int j0 = jt*64, cur = jt & 1, nxt = cur ^ 1;
    // issue next tile's staging; current tile's loads (issued last iter) are
    // awaited with a COUNTED vmcnt so these stay in flight across the barrier.
    if (jt < 15){
      const int jn = j0 + 64;
      #pragma unroll
      for (int r = 0; r < 2; ++r){
        gload16(kg + jn*64 + kOff[r], &lKV[nxt*4096 + dst[r]]);
        gload16(vg + jn + vOff[r],    &lKV[(2 + nxt)*4096 + dst[r]]);
      }
      asm volatile("s_waitcnt vmcnt(4)" ::: "memory");
    } else {
      asm volatile("s_waitcnt vmcnt(0)" ::: "memory");
    }
    asm volatile("s_barrier" ::: "memory");   // tile jt staged by all waves

    const bf16* Kc = lKV + cur*4096;
    const bf16* Vc = lKV + (2 + cur)*4096;

    // S^T tiles: lane holds 16 scores for its own q row
    f32x4 s[4] = {};
    __builtin_amdgcn_s_setprio(1);
    #pragma unroll
    for (int ni = 0; ni < 4; ++ni){
      const int row = ni*16 + cl;
      short8 k0f = *(const short8*)&Kc[row*64 + ((g ^ (row & 7))*8)];
      s[ni] = mfma16(k0f, aq0, s[ni]);
      short8 k1f = *(const short8*)&Kc[row*64 + (((g + 4) ^ (row & 7))*8)];
      s[ni] = mfma16(k1f, aq1, s[ni]);
    }
    __builtin_amdgcn_s_setprio(0);

    const int dj = j0 - i0;
    if (dj == 0 || dj == 64 || dj == -64){
      #pragma unroll
      for (int ni = 0; ni < 4; ++ni){
        const int ibase = j0 + koffA[ni] - qt;
        #pragma unroll
        for (int r = 0; r < 4; ++r){
          const int dd = ibase + r;
          float v = s[ni][r] - __log2f(fabsf((float)dd) + 1.0f);
          if ((unsigned)(dd + 10) <= 20u){
            v += b2f(*(const short*)&relkD[ql*22 + dd + 10]);
            bandS[ql*21 + dd + 10] = v;
          }
          s[ni][r] = v;
        }
      }
    } else {
      // off-band: |dd| >= 65, linearize log2(1+|dd+r|) around r=0
      // (max error ~0.0015 log2-units -> ~0.1% in p, below bf16 noise)
      #pragma unroll
      for (int ni = 0; ni < 4; ++ni){
        const float fb = (float)(j0 + koffA[ni] - qt);
        const float x1 = fabsf(fb) + 1.0f;
        const float base = __log2f(x1);
        const float slope = __builtin_copysignf(1.44269504f, fb) *
                            __builtin_amdgcn_rcpf(x1);
        #pragma unroll
        for (int r = 0; r < 4; ++r)
          s[ni][r] -= __builtin_fmaf((float)r, slope, base);
      }
    }

    // lane-local online softmax (log2 domain), defer-max threshold 8
    float m0 = fmaxf(fmaxf(s[0][0], s[0][1]), fmaxf(s[0][2], s[0][3]));
    float m1 = fmaxf(fmaxf(s[1][0], s[1][1]), fmaxf(s[1][2], s[1][3]));
    float m2 = fmaxf(fmaxf(s[2][0], s[2][1]), fmaxf(s[2][2], s[2][3]));
    float m3 = fmaxf(fmaxf(s[3][0], s[3][1]), fmaxf(s[3][2], s[3][3]));
    float mx = fmaxf(fmaxf(m0, m1), fmaxf(m2, m3));
    mx = fmaxf(mx, __shfl_xor(mx, 16));
    mx = fmaxf(mx, __shfl_xor(mx, 32));
    if (!__all(mx <= mreg + 8.0f)){
      const float mn = fmaxf(mreg, mx);
      const float sc = __builtin_amdgcn_exp2f(mreg - mn);
      lreg *= sc;
      #pragma unroll
      for (int di = 0; di < 4; ++di)
        #pragma unroll
        for (int r = 0; r < 4; ++r) o[di][r] *= sc;
      mreg = mn;
    }
    #pragma unroll
    for (int ni = 0; ni < 4; ++ni)
      #pragma unroll
      for (int r = 0; r < 4; ++r)
        s[ni][r] = __builtin_amdgcn_exp2f(s[ni][r] - mreg);

    // pack P in-register: frag0 = {ni0, ni2}, frag1 = {ni1, ni3}
    PkU bf0, bf1;
    bf0.i[0] = cvtpk(s[0][0], s[0][1]); bf0.i[1] = cvtpk(s[0][2], s[0][3]);
    bf0.i[2] = cvtpk(s[2][0], s[2][1]); bf0.i[3] = cvtpk(s[2][2], s[2][3]);
    bf1.i[0] = cvtpk(s[1][0], s[1][1]); bf1.i[1] = cvtpk(s[1][2], s[1][3]);
    bf1.i[2] = cvtpk(s[3][0], s[3][1]); bf1.i[3] = cvtpk(s[3][2], s[3][3]);

    __builtin_amdgcn_s_setprio(1);
    #pragma unroll
    for (int di = 0; di < 4; ++di){
      const int vrow = di*16 + cl;
      short8 a0 = *(const short8*)&Vc[vrow*64 + ((g ^ (vrow & 7))*8)];
      o[di] = mfma16(a0, bf0.v, o[di]);
      short8 a1 = *(const short8*)&Vc[vrow*64 + (((g + 4) ^ (vrow & 7))*8)];
      o[di] = mfma16(a1, bf1.v, o[di]);
    }
    __builtin_amdgcn_s_setprio(0);

    // row-sum after PV issue: independent of cvtpk->MFMA path, overlaps drain
    float rs = 0.f;
    #pragma unroll
    for (int ni = 0; ni < 4; ++ni)
      rs += (s[ni][0] + s[ni][1]) + (s[ni][2] + s[ni][3]);
    rs += __shfl_xor(rs, 16);
    rs += __shfl_xor(rs, 32);
    lreg += rs;

    asm volatile("s_barrier" ::: "memory");   // all reads of tile jt done
  }

  // epilogue: rel-v band contribution via MFMA (A staged over dead K buf0)
  for (int idx = tid; idx < 2048; idx += 256){
    const int d = idx >> 5, c = idx & 31;
    const float v = (c < 21) ? relv[c*64 + d] : 0.0f;
    lEV[d*32 + (((c >> 3) ^ ((d >> 2) & 3))*8) + (c & 7)] = (bf16)v;
  }
  __syncthreads();

  const float invl = 1.0f / lreg;
  float pb[8];
  #pragma unroll
  for (int e = 0; e < 8; ++e){
    const int ddi = 8*g + e;
    float pv = 0.f;
    if (ddi < 21){
      const int j = qt + ddi - 10;
      if (j >= 0 && j < T)
        pv = __builtin_amdgcn_exp2f(bandS[ql*21 + ddi] - mreg) * invl;
    }
    pb[e] = pv;
  }
  PkU bfE;
  bfE.i[0] = cvtpk(pb[0], pb[1]); bfE.i[1] = cvtpk(pb[2], pb[3]);
  bfE.i[2] = cvtpk(pb[4], pb[5]); bfE.i[3] = cvtpk(pb[6], pb[7]);

  bf16* outp = aws + (size_t)(b*T + qt)*C + h*64;
  #pragma unroll
  for (int di = 0; di < 4; ++di){
    const int arow = di*16 + cl;
    short8 aE = *(const short8*)&lEV[arow*32 + ((g ^ ((arow >> 2) & 3))*8)];
    f32x4 z = {};
    f32x4 ba = mfma16(aE, bfE.v, z);
    const int p0 = cvtpk(o[di][0]*invl + ba[0], o[di][1]*invl + ba[1]);
    const int p1 = cvtpk(o[di][2]*invl + ba[2], o[di][3]*invl + ba[3]);
    *(int2*)(outp + di*16 + 4*g) = make_int2(p0, p1);
  }
}

extern "C" void kernel_launch(void* const* d_in, const int* in_sizes, int n_in,
                              void* d_out, int out_size, void* d_ws, size_t ws_size,
                              hipStream_t stream){
  const float* x    = (const float*)d_in[0];
  const float* cin  = (const float*)d_in[1];
  const float* Wq   = (const float*)d_in[2];
  const float* bq   = (const float*)d_in[3];
  const float* Wk   = (const float*)d_in[4];
  const float* bk   = (const float*)d_in[5];
  const float* Wv   = (const float*)d_in[6];
  const float* bv   = (const float*)d_in[7];
  const float* Wo   = (const float*)d_in[8];
  const float* bo   = (const float*)d_in[9];
  const float* relk = (const float*)d_in[10];
  const float* relv = (const float*)d_in[11];

  char* ws = (char*)d_ws;
  constexpr size_t SZ_W = (size_t)768*768*2;     // bf16 weight matrix
  constexpr size_t SZ_T = (size_t)4*1024*768*2;  // bf16 [B,T,C]-sized tensor
  bf16* wq  = (bf16*)(ws + 0*SZ_W);
  bf16* wk  = (bf16*)(ws + 1*SZ_W);
  bf16* wv  = (bf16*)(ws + 2*SZ_W);
  bf16* wo  = (bf16*)(ws + 3*SZ_W);
  bf16* xb  = (bf16*)(ws + 4*SZ_W);
  bf16* cb  = (bf16*)(ws + 4*SZ_W + 1*SZ_T);
  bf16* qws = (bf16*)(ws + 4*SZ_W + 2*SZ_T);
  bf16* kws = (bf16*)(ws + 4*SZ_W + 3*SZ_T);
  bf16* vws = (bf16*)(ws + 4*SZ_W + 4*SZ_T);
  bf16* attn = xb;   // alias: xb is dead after the Q projection

  prep_kernel<<<dim3(16,12,20), 256, 0, stream>>>(x, cin, Wq, Wk, Wv, Wo,
                                                  xb, cb, wq, wk, wv, wo);
  gemm_qkv<<<dim3(48,12), 256, 0, stream>>>(xb, cb, wq, wk, wv, bq, bk, bv, qws, kws, vws);
  attn_kernel<<<dim3(48,16), 256, 0, stream>>>(qws, kws, vws, attn, relk, relv);
  gemm_o<<<dim3(6,8,4), 256, 0, stream>>>(wo, attn, bo, (float*)d_out);
}